// Round 2
// baseline (103.992 us; speedup 1.0000x reference)
//
#include <hip/hip_runtime.h>

#define N 1024
#define D 128
#define PAD 132            // 128+4: rows 16B-aligned, bank stride 4 -> 2-way (free)
#define MAGIC 0x3C96A5E1u  // "counter initialized" flag value (ws is poisoned)
#define NBLK 512           // total blocks; all must be co-resident for the barrier

// ---------------------------------------------------------------------------
// Fused scores+relu+exp+rowsum+normalize with in-kernel grid barrier.
// Round-1 lesson: 64x64 tiles -> 256 blocks -> 1 wave/SIMD killed it.
// This round: round-0's proven geometry (64x32 tile, 512 blocks, micro 4x2,
// 2-3 blocks/CU) + fusion.
//
// Row-sum protocol (no atomics, no zeroing):
//   part[row][cb] (1024x32 f32 in ws) -- each block writes its own column cb,
//   every word written, so no init required. Only flag+counter (2 words) need
//   init by block (0,0). After the barrier each block re-reduces its 64 rows'
//   32 partials from L2 (8 KB, shared by the 32 blocks of a row-stripe).
//
// Co-residency: LDS 49.8 KB -> 3 blocks/CU; VGPR ~<128 -> >=2; capacity
// >= 512. Spins are iteration-capped: protocol failure = wrong answer, not
// a hang. ws is re-poisoned every iteration (the 256 MiB fills in the trace),
// so flag != MAGIC at each entry.
// ---------------------------------------------------------------------------
__global__ __launch_bounds__(256) void fused_kernel(
    const float* __restrict__ x, const float* __restrict__ w,
    const float* __restrict__ bias, float* __restrict__ S,
    unsigned int* __restrict__ ws) {
  __shared__ float sxi[64 * PAD];
  __shared__ float sxj[32 * PAD];
  __shared__ float srow[64];

  unsigned int* flag    = ws;        // ws + 0
  unsigned int* counter = ws + 32;   // ws + 128 B (own cache line)
  float* part = reinterpret_cast<float*>(ws) + 1024;  // [1024][32] f32, 128 KB

  const int t  = threadIdx.x;
  const int bi = blockIdx.y * 64;   // row base
  const int bj = blockIdx.x * 32;   // col base
  const int cb = blockIdx.x;        // this block's partial-sum column

  // ---- block (0,0): init counter, release flag (single thread, no barrier) --
  if (blockIdx.x == 0 && blockIdx.y == 0 && t == 0) {
    __hip_atomic_store(counter, 0u, __ATOMIC_RELAXED, __HIP_MEMORY_SCOPE_AGENT);
    __threadfence();
    __hip_atomic_store(flag, MAGIC, __ATOMIC_RELEASE, __HIP_MEMORY_SCOPE_AGENT);
  }

  // ---- stage tiles: coalesced float4 global reads, one barrier --------------
  {
    const int c  = t & 31;   // float4 index within a 128-float row
    const int r0 = t >> 5;   // 0..7
    #pragma unroll
    for (int p = 0; p < 8; ++p) {   // 64 rows of xi
      const int r = r0 + p * 8;
      const float4 v = reinterpret_cast<const float4*>(x)[(bi + r) * 32 + c];
      *reinterpret_cast<float4*>(&sxi[r * PAD + c * 4]) = v;
    }
    #pragma unroll
    for (int p = 0; p < 4; ++p) {   // 32 rows of xj
      const int r = r0 + p * 8;
      const float4 v = reinterpret_cast<const float4*>(x)[(bj + r) * 32 + c];
      *reinterpret_cast<float4*>(&sxj[r * PAD + c * 4]) = v;
    }
  }
  __syncthreads();

  const int tx = t & 15;   // col group: cols tx + 16*b, b=0..1
  const int ty = t >> 4;   // row group: rows ty + 16*a, a=0..3

  float acc[4][2];
  #pragma unroll
  for (int a = 0; a < 4; ++a)
    #pragma unroll
    for (int b = 0; b < 2; ++b) acc[a][b] = 0.f;

  #pragma unroll 4
  for (int d = 0; d < D; d += 4) {
    const float4 W = reinterpret_cast<const float4*>(w)[d >> 2];  // s_load
    float4 A[4], B[2];
    #pragma unroll
    for (int a = 0; a < 4; ++a)   // 4 addrs/wave, 16-lane broadcast
      A[a] = *reinterpret_cast<const float4*>(&sxi[(ty + 16 * a) * PAD + d]);
    #pragma unroll
    for (int b = 0; b < 2; ++b)   // 16 addrs/wave, 2-way alias (free)
      B[b] = *reinterpret_cast<const float4*>(&sxj[(tx + 16 * b) * PAD + d]);

    #pragma unroll
    for (int a = 0; a < 4; ++a) {
      #pragma unroll
      for (int b = 0; b < 2; ++b) {
        float s = acc[a][b];
        s = fmaf(fabsf(A[a].x - B[b].x), W.x, s);
        s = fmaf(fabsf(A[a].y - B[b].y), W.y, s);
        s = fmaf(fabsf(A[a].z - B[b].z), W.z, s);
        s = fmaf(fabsf(A[a].w - B[b].w), W.w, s);
        acc[a][b] = s;
      }
    }
  }

  // ---- epilogue: relu + exp (no max-sub; scores >= 0, bounded) --------------
  // exp values stay in registers across the barrier; S written exactly once.
  const float bv = bias[0];
  float e[4][2];
  #pragma unroll
  for (int a = 0; a < 4; ++a) {
    float p = 0.f;
    #pragma unroll
    for (int b = 0; b < 2; ++b) {
      const float s  = fmaxf(acc[a][b] + bv, 0.f);
      const float ev = __expf(s);
      e[a][b] = ev;
      p += ev;
    }
    // reduce across the 16-lane tx group (xor<16 keeps ty constant)
    #pragma unroll
    for (int o = 1; o < 16; o <<= 1) p += __shfl_xor(p, o, 64);
    // one lane per row writes this block's partial (own slot, no atomic)
    if (tx == 0)
      __hip_atomic_store(&part[(bi + ty + 16 * a) * 32 + cb], p,
                         __ATOMIC_RELAXED, __HIP_MEMORY_SCOPE_AGENT);
  }
  __syncthreads();   // drains vmcnt: all 64 partial stores of this block issued

  // ---- grid barrier: wait init flag, arrive, spin ---------------------------
  if (t == 0) {
    for (unsigned it = 0; it < (1u << 24); ++it) {
      if (__hip_atomic_load(flag, __ATOMIC_ACQUIRE,
                            __HIP_MEMORY_SCOPE_AGENT) == MAGIC) break;
      __builtin_amdgcn_s_sleep(2);
    }
    __threadfence();   // partial stores visible before arrival is visible
    __hip_atomic_fetch_add(counter, 1u, __ATOMIC_ACQ_REL,
                           __HIP_MEMORY_SCOPE_AGENT);
    for (unsigned it = 0; it < (1u << 24); ++it) {
      if (__hip_atomic_load(counter, __ATOMIC_ACQUIRE,
                            __HIP_MEMORY_SCOPE_AGENT) >= NBLK) break;
      __builtin_amdgcn_s_sleep(2);
    }
  }
  __syncthreads();

  // ---- reduce the 32 partials per row (L2-hot, 8 KB per row-stripe) ---------
  {
    const int r = t >> 2;          // 0..63: local row
    const int q = t & 3;           // 4 threads per row, 8 slots each
    float s = 0.f;
    #pragma unroll
    for (int k = 0; k < 8; ++k)
      s += __hip_atomic_load(&part[(bi + r) * 32 + q * 8 + k],
                             __ATOMIC_RELAXED, __HIP_MEMORY_SCOPE_AGENT);
    s += __shfl_xor(s, 1, 64);
    s += __shfl_xor(s, 2, 64);
    if (q == 0) srow[r] = s;
  }
  __syncthreads();

  // ---- normalize from registers, single write of S --------------------------
  float rs[4];
  #pragma unroll
  for (int a = 0; a < 4; ++a) rs[a] = 1.0f / srow[ty + 16 * a];

  #pragma unroll
  for (int a = 0; a < 4; ++a) {
    const int row = bi + ty + 16 * a;
    #pragma unroll
    for (int b = 0; b < 2; ++b)
      S[row * N + bj + tx + 16 * b] = e[a][b] * rs[a];
  }
}

extern "C" void kernel_launch(void* const* d_in, const int* in_sizes, int n_in,
                              void* d_out, int out_size, void* d_ws, size_t ws_size,
                              hipStream_t stream) {
  const float* x = (const float*)d_in[0];
  const float* w = (const float*)d_in[1];
  const float* b = (const float*)d_in[2];
  float* out = (float*)d_out;
  unsigned int* ws = (unsigned int*)d_ws;

  dim3 grid(N / 32, N / 64);   // (32,16) = 512 blocks, 2-3/CU, all co-resident
  fused_kernel<<<grid, 256, 0, stream>>>(x, w, b, out, ws);
}

// Round 3
// 75.256 us; speedup vs baseline: 1.3818x; 1.3818x over previous
//
#include <hip/hip_runtime.h>

#define N 1024
#define D 128
#define PAD 132   // 128+4: rows 16B-aligned (528 B), A reads conflict-free, B reads 2-way (free)

// ---------------------------------------------------------------------------
// Phase A: E[i][j] = exp(relu(sum_d |x[i][d]-x[j][d]| * w[d] + bias)), plus
// per-block row partial sums part[row][cb] (no atomics, every slot written,
// so the poisoned ws needs no init).
//
// Geometry (round-3): tile 64x64, micro 4x4, 1024 threads as 4 d-groups of
// 256 (split-d). Group g computes partial acc over d in [32g, 32g+32); groups
// 1-3 dump partials to LDS (reusing the tile space), group 0 combines and
// runs the epilogue. Grid = 256 blocks -> 1 block/CU, 16 waves/CU = 4/SIMD
// (round-0 had 2/SIMD), and LDS traffic per FLOP is halved vs micro 4x2
// (268 MB vs 403 MB grid-wide). No grid barrier (round-2: single-counter
// barrier cost ~30 us from cross-XCD cacheline ping-pong).
// ---------------------------------------------------------------------------
__global__ __launch_bounds__(1024, 4) void scores_kernel(
    const float* __restrict__ x, const float* __restrict__ w,
    const float* __restrict__ bias, float* __restrict__ E,
    float* __restrict__ part) {
  __shared__ float smem[2 * 64 * PAD];   // sxi | sxj ; combine buffer aliases
  float* sxi = smem;
  float* sxj = smem + 64 * PAD;

  const int t  = threadIdx.x;
  const int bi = blockIdx.y * 64;
  const int bj = blockIdx.x * 64;

  // ---- stage both 64-row tiles: coalesced float4, 4 loads/thread ----------
  {
    const int c  = t & 31;   // float4 column 0..31
    const int r0 = t >> 5;   // 0..31
    #pragma unroll
    for (int p = 0; p < 2; ++p) {
      const int r = r0 + p * 32;
      const float4 vi = reinterpret_cast<const float4*>(x)[(bi + r) * 32 + c];
      *reinterpret_cast<float4*>(&sxi[r * PAD + c * 4]) = vi;
      const float4 vj = reinterpret_cast<const float4*>(x)[(bj + r) * 32 + c];
      *reinterpret_cast<float4*>(&sxj[r * PAD + c * 4]) = vj;
    }
  }
  __syncthreads();

  // d-group (wave-uniform: 1024 threads -> t>>8 constant within each wave;
  // readfirstlane pins it to an SGPR so W loads stay scalar)
  const int g  = __builtin_amdgcn_readfirstlane(t >> 8);   // 0..3
  const int s  = t & 255;                                  // slot in group
  const int tx = s & 15;   // cols tx + 16*b
  const int ty = s >> 4;   // rows ty + 16*a
  const int d0 = g * 32;

  float acc[4][4];
  #pragma unroll
  for (int a = 0; a < 4; ++a)
    #pragma unroll
    for (int b = 0; b < 4; ++b) acc[a][b] = 0.f;

  #pragma unroll 2
  for (int dc = 0; dc < 8; ++dc) {     // 8 chunks of 4 d-values
    const float4 W = reinterpret_cast<const float4*>(w)[(d0 >> 2) + dc];
    const int d = d0 + dc * 4;
    float4 A[4], B[4];
    #pragma unroll
    for (int a = 0; a < 4; ++a)   // 4 addrs/wave, 16-lane broadcast, no conflict
      A[a] = *reinterpret_cast<const float4*>(&sxi[(ty + 16 * a) * PAD + d]);
    #pragma unroll
    for (int b = 0; b < 4; ++b)   // 16 addrs/wave, 2-way alias (free)
      B[b] = *reinterpret_cast<const float4*>(&sxj[(tx + 16 * b) * PAD + d]);

    #pragma unroll
    for (int a = 0; a < 4; ++a) {
      #pragma unroll
      for (int b = 0; b < 4; ++b) {
        float v = acc[a][b];
        v = fmaf(fabsf(A[a].x - B[b].x), W.x, v);
        v = fmaf(fabsf(A[a].y - B[b].y), W.y, v);
        v = fmaf(fabsf(A[a].z - B[b].z), W.z, v);
        v = fmaf(fabsf(A[a].w - B[b].w), W.w, v);
        acc[a][b] = v;
      }
    }
  }
  __syncthreads();   // tiles dead; smem becomes the combine buffer

  // ---- combine the 4 d-partials: groups 1-3 write, group 0 sums -----------
  // layout [3][256][17]: stride 17 -> 2-way bank alias only (free)
  float* comb = smem;
  if (g > 0) {
    float* dst = comb + ((g - 1) * 256 + s) * 17;
    #pragma unroll
    for (int k = 0; k < 16; ++k) dst[k] = acc[k >> 2][k & 3];
  }
  __syncthreads();

  if (g == 0) {
    #pragma unroll
    for (int q = 0; q < 3; ++q) {
      const float* src = comb + (q * 256 + s) * 17;
      #pragma unroll
      for (int k = 0; k < 16; ++k) acc[k >> 2][k & 3] += src[k];
    }

    // ---- epilogue: bias + relu + exp (no max-sub: scores >= 0, sigma~1.4,
    // exp bounded ~1e3, fp32-safe; identical numerics passed round 2) ------
    const float bv = bias[0];
    #pragma unroll
    for (int a = 0; a < 4; ++a) {
      float p = 0.f;
      #pragma unroll
      for (int b = 0; b < 4; ++b) {
        const float ev = __expf(fmaxf(acc[a][b] + bv, 0.f));
        acc[a][b] = ev;
        p += ev;
      }
      #pragma unroll
      for (int o = 1; o < 16; o <<= 1) p += __shfl_xor(p, o, 64);
      if (tx == 0) part[(bi + ty + 16 * a) * 16 + blockIdx.x] = p;
    }

    #pragma unroll
    for (int a = 0; a < 4; ++a) {
      const int row = bi + ty + 16 * a;
      #pragma unroll
      for (int b = 0; b < 4; ++b)
        E[row * N + bj + tx + 16 * b] = acc[a][b];
    }
  }
}

// ---------------------------------------------------------------------------
// Phase B: scale pass. One block per row: sum the 16 partials (redundant
// per-wave shuffle reduce, L2-hot), multiply the row in place.
// ---------------------------------------------------------------------------
__global__ __launch_bounds__(256) void scale_kernel(
    float* __restrict__ S, const float* __restrict__ part) {
  const int row = blockIdx.x;
  const int t   = threadIdx.x;

  float p = part[row * 16 + (t & 15)];
  #pragma unroll
  for (int o = 1; o < 16; o <<= 1) p += __shfl_xor(p, o, 64);
  const float r = 1.0f / p;

  float4* rowp = reinterpret_cast<float4*>(S + row * N);
  float4 v = rowp[t];
  v.x *= r; v.y *= r; v.z *= r; v.w *= r;
  rowp[t] = v;
}

extern "C" void kernel_launch(void* const* d_in, const int* in_sizes, int n_in,
                              void* d_out, int out_size, void* d_ws, size_t ws_size,
                              hipStream_t stream) {
  const float* x = (const float*)d_in[0];
  const float* w = (const float*)d_in[1];
  const float* b = (const float*)d_in[2];
  float* out  = (float*)d_out;
  float* part = (float*)d_ws;   // [1024][16] f32, every slot written by phase A

  dim3 grid(N / 64, N / 64);    // (16,16) = 256 blocks, 1/CU, 16 waves/CU
  scores_kernel<<<grid, 1024, 0, stream>>>(x, w, b, out, part);
  scale_kernel<<<N, 256, 0, stream>>>(out, part);
}

// Round 4
// 72.827 us; speedup vs baseline: 1.4279x; 1.0334x over previous
//
#include <hip/hip_runtime.h>

#define N 1024
#define D 128
#define PAD 132   // 128+4: rows 16B-aligned (528 B), bank stride 4 -> 2-way (free)

// ---------------------------------------------------------------------------
// Phase A: E[i][j] = exp(relu(sum_d |x[i][d]-x[j][d]| * w[d] + bias)), plus
// per-block row partials part[row][bx] (every slot written -> poisoned ws
// needs no init, no atomics).
//
// KEY FIX (round 4): no SMEM (s_load) inside the d-loop. Previous rounds
// loaded W from global each chunk -> s_waitcnt lgkmcnt(0) (SMEM is
// out-of-order) -> drained all outstanding ds_reads to full latency every
// chunk. W now lives in LDS: the loop is pure ds_read + VALU, so the
// compiler emits counted lgkmcnt(N) and ds-latency pipelines across chunks.
//
// Geometry: 64x32 tile, 512 threads = 2 d-groups x 256 (split-d over 64 d
// each), micro 4x2. Grid 512 blocks -> 2 blocks/CU, 16 waves/CU = 4/SIMD.
// LDS 50.9 KB/block -> 2 blocks/CU fits (101.8 < 160 KB).
// ---------------------------------------------------------------------------
__global__ __launch_bounds__(512, 4) void scores_kernel(
    const float* __restrict__ x, const float* __restrict__ w,
    const float* __restrict__ bias, float* __restrict__ E,
    float* __restrict__ part) {
  __shared__ float sxi[64 * PAD];   // 33.8 KB; combine buffer aliases this
  __shared__ float sxj[32 * PAD];   // 16.9 KB
  __shared__ float sw[D];           // 512 B

  const int t  = threadIdx.x;
  const int bi = blockIdx.y * 64;
  const int bj = blockIdx.x * 32;

  // ---- stage tiles + w: coalesced float4, one barrier ----------------------
  {
    const int c  = t & 31;   // float4 column 0..31
    const int r0 = t >> 5;   // 0..15
    #pragma unroll
    for (int p = 0; p < 4; ++p) {   // 64 rows of xi
      const int r = r0 + p * 16;
      const float4 v = reinterpret_cast<const float4*>(x)[(bi + r) * 32 + c];
      *reinterpret_cast<float4*>(&sxi[r * PAD + c * 4]) = v;
    }
    #pragma unroll
    for (int p = 0; p < 2; ++p) {   // 32 rows of xj
      const int r = r0 + p * 16;
      const float4 v = reinterpret_cast<const float4*>(x)[(bj + r) * 32 + c];
      *reinterpret_cast<float4*>(&sxj[r * PAD + c * 4]) = v;
    }
    if (t < 32)
      *reinterpret_cast<float4*>(&sw[t * 4]) =
          reinterpret_cast<const float4*>(w)[t];
  }
  __syncthreads();

  // d-group: wave-uniform (waves 0-3 -> g=0, waves 4-7 -> g=1)
  const int g  = __builtin_amdgcn_readfirstlane(t >> 8);   // 0..1
  const int s  = t & 255;                                  // slot in group
  const int tx = s & 15;   // cols tx + 16*b, b=0..1
  const int ty = s >> 4;   // rows ty + 16*a, a=0..3
  const int d0 = g * 64;   // this group's d-range base

  float acc[4][2];
  #pragma unroll
  for (int a = 0; a < 4; ++a)
    #pragma unroll
    for (int b = 0; b < 2; ++b) acc[a][b] = 0.f;

  #pragma unroll 4
  for (int dc = 0; dc < 16; ++dc) {   // 16 chunks of 4 d-values (64 per group)
    const int d = d0 + dc * 4;
    // W from LDS: wave-uniform address -> broadcast, no SMEM in the loop
    const float4 W = *reinterpret_cast<const float4*>(&sw[d]);
    float4 A[4], B[2];
    #pragma unroll
    for (int a = 0; a < 4; ++a)   // 4 addrs/wave, 16-lane broadcast
      A[a] = *reinterpret_cast<const float4*>(&sxi[(ty + 16 * a) * PAD + d]);
    #pragma unroll
    for (int b = 0; b < 2; ++b)   // 16 addrs/wave, 2-way alias (free)
      B[b] = *reinterpret_cast<const float4*>(&sxj[(tx + 16 * b) * PAD + d]);

    #pragma unroll
    for (int a = 0; a < 4; ++a) {
      #pragma unroll
      for (int b = 0; b < 2; ++b) {
        float v = acc[a][b];
        v = fmaf(fabsf(A[a].x - B[b].x), W.x, v);
        v = fmaf(fabsf(A[a].y - B[b].y), W.y, v);
        v = fmaf(fabsf(A[a].z - B[b].z), W.z, v);
        v = fmaf(fabsf(A[a].w - B[b].w), W.w, v);
        acc[a][b] = v;
      }
    }
  }
  __syncthreads();   // tiles dead; sxi becomes the combine buffer

  // ---- combine the 2 d-partials: g1 writes, g0 sums ------------------------
  // layout [256][9]: odd word stride -> 2-way bank alias only (free)
  float* comb = sxi;
  if (g == 1) {
    float* dst = comb + s * 9;
    #pragma unroll
    for (int k = 0; k < 8; ++k) dst[k] = acc[k >> 1][k & 1];
  }
  __syncthreads();

  if (g == 0) {
    const float* src = comb + s * 9;
    #pragma unroll
    for (int k = 0; k < 8; ++k) acc[k >> 1][k & 1] += src[k];

    // ---- epilogue: bias + relu + exp (no max-sub: scores >= 0, bounded,
    // fp32-safe; identical numerics passed rounds 2-3, absmax 0.0) ----------
    const float bv = bias[0];
    #pragma unroll
    for (int a = 0; a < 4; ++a) {
      float p = 0.f;
      #pragma unroll
      for (int b = 0; b < 2; ++b) {
        const float ev = __expf(fmaxf(acc[a][b] + bv, 0.f));
        acc[a][b] = ev;
        p += ev;
      }
      // reduce across the 16-lane tx group (xor<16 keeps ty fixed)
      #pragma unroll
      for (int o = 1; o < 16; o <<= 1) p += __shfl_xor(p, o, 64);
      if (tx == 0) part[(bi + ty + 16 * a) * 32 + blockIdx.x] = p;
    }

    #pragma unroll
    for (int a = 0; a < 4; ++a) {
      const int row = bi + ty + 16 * a;
      #pragma unroll
      for (int b = 0; b < 2; ++b)
        E[row * N + bj + tx + 16 * b] = acc[a][b];
    }
  }
}

// ---------------------------------------------------------------------------
// Phase B: scale pass. One block per row: sum 32 partials (L2-hot), scale.
// ---------------------------------------------------------------------------
__global__ __launch_bounds__(256) void scale_kernel(
    float* __restrict__ S, const float* __restrict__ part) {
  const int row = blockIdx.x;
  const int t   = threadIdx.x;

  float p = part[row * 32 + (t & 31)];
  #pragma unroll
  for (int o = 1; o < 32; o <<= 1) p += __shfl_xor(p, o, 64);
  const float r = 1.0f / p;

  float4* rowp = reinterpret_cast<float4*>(S + row * N);
  float4 v = rowp[t];
  v.x *= r; v.y *= r; v.z *= r; v.w *= r;
  rowp[t] = v;
}

extern "C" void kernel_launch(void* const* d_in, const int* in_sizes, int n_in,
                              void* d_out, int out_size, void* d_ws, size_t ws_size,
                              hipStream_t stream) {
  const float* x = (const float*)d_in[0];
  const float* w = (const float*)d_in[1];
  const float* b = (const float*)d_in[2];
  float* out  = (float*)d_out;
  float* part = (float*)d_ws;   // [1024][32] f32 = 128 KB, every slot written

  dim3 grid(N / 32, N / 64);    // (32,16) = 512 blocks, 2/CU, 4 waves/SIMD
  scores_kernel<<<grid, 512, 0, stream>>>(x, w, b, out, part);
  scale_kernel<<<N, 256, 0, stream>>>(out, part);
}